// Round 7
// baseline (177.844 us; speedup 1.0000x reference)
//
#include <hip/hip_runtime.h>

typedef unsigned short u16;
typedef unsigned int   u32;
typedef __attribute__((ext_vector_type(8))) short bf16x8;
typedef __attribute__((ext_vector_type(4))) short s16x4;
typedef __attribute__((ext_vector_type(4))) float f32x4;

#define MFMA16(a,b,c) __builtin_amdgcn_mfma_f32_16x16x32_bf16((a),(b),(c),0,0,0)

__device__ __forceinline__ float bf2f(u16 u){ return __uint_as_float(((u32)u)<<16); }
__device__ __forceinline__ u16 f2bf(float f){
  u32 u = __float_as_uint(f);
  return (u16)((u + 0x7fffu + ((u>>16)&1u)) >> 16);
}
__device__ __forceinline__ u32 encf(float f){ u32 u=__float_as_uint(f); return (u&0x80000000u)? ~u : (u|0x80000000u); }
__device__ __forceinline__ float decf(u32 u){ return (u&0x80000000u)? __uint_as_float(u&0x7fffffffu) : __uint_as_float(~u); }

// async global->LDS, 16B per lane, LDS dest = wave-uniform base + lane*16
__device__ __forceinline__ void async_lds16(u16* lds, const u16* g){
  __builtin_amdgcn_global_load_lds((const __attribute__((address_space(1))) void*)g,
                                   (__attribute__((address_space(3))) void*)lds,
                                   16, 0, 0);
}

// stage ROWS x 64 bf16 from global (srcStride elems) into LDS padded to 72/row
template<int ROWS>
__device__ __forceinline__ void stage64(u16* dst, const u16* src, int srcStride, int tid){
  #pragma unroll
  for (int u=tid; u<ROWS*8; u+=256){
    int r=u>>3, c=(u&7)<<3;
    *(int4*)&dst[r*72+c] = *(const int4*)&src[(size_t)r*srcStride + c];
  }
}

// ---------------- init: kmax=0, projS=dn*proj (bf16), x->bf16, vTA ones/zero rows ----------------
__global__ void k_init(u32* kmaxEnc, u16* projS, u16* vTA,
                       const float* __restrict__ proj, const float* __restrict__ x, u16* __restrict__ xb){
  int i = blockIdx.x*blockDim.x + threadIdx.x;
  int st = gridDim.x*blockDim.x;
  for (int j=i; j<32; j+=st) kmaxEnc[j]=0u;
  const float dn = 0.35355339059327373f; // 64^-0.25
  for (int j=i; j<512*64; j+=st) projS[j] = f2bf(dn*proj[j]);
  for (int j=i; j<524288; j+=st){
    float4 a = *(const float4*)&x[(size_t)j*8];
    float4 b = *(const float4*)&x[(size_t)j*8+4];
    u16 tmp[8] = {f2bf(a.x),f2bf(a.y),f2bf(a.z),f2bf(a.w),
                  f2bf(b.x),f2bf(b.y),f2bf(b.z),f2bf(b.w)};
    *(int4*)&xb[(size_t)j*8] = *(const int4*)tmp;
  }
  // vTA rows 64..79: row 64 = ones (for kcs via GEMM), rest zero
  for (int j=i; j<1048576; j+=st){
    int gbh = j>>15, rr = (j>>11)&15, n = j&2047;
    vTA[(size_t)gbh*80*2048 + (size_t)(64+rr)*2048 + n] = (rr==0) ? (u16)0x3F80 : (u16)0;
  }
}

// ---------------- fp32 512x512 -> bf16 transpose, batched over 4 weights ----------------
__global__ __launch_bounds__(256) void k_trw(const float* s0, const float* s1, const float* s2, const float* s3,
                                             u16* d0, u16* d1, u16* d2, u16* d3){
  int z = blockIdx.z;
  const float* src = z==0?s0:(z==1?s1:(z==2?s2:s3));
  u16* dst         = z==0?d0:(z==1?d1:(z==2?d2:d3));
  __shared__ u16 t[32][34];
  int c0=blockIdx.x*32, r0=blockIdx.y*32;
  int tid=threadIdx.x;
  for (int u=tid; u<1024; u+=256){ int r=u>>5, c=u&31; t[r][c]=f2bf(src[(size_t)(r0+r)*512 + c0+c]); }
  __syncthreads();
  for (int u=tid; u<1024; u+=256){ int c=u>>5, r=u&31; dst[(size_t)(c0+c)*512 + r0+r]=t[r][c]; }
}

// ---------------- v (per b,h 2048x64 slice of [t][512]) -> vTA[bh][80][2048] rows 0-63 ----------------
__global__ __launch_bounds__(256) void k_trv(const u16* __restrict__ v, u16* __restrict__ vTA){
  int bh = blockIdx.z; int b=bh>>3, h=bh&7;
  int d0 = blockIdx.x*32, n0 = blockIdx.y*32;
  __shared__ u16 t[32][34];
  int tid=threadIdx.x;
  const u16* s = v + (size_t)(b*2048)*512 + h*64;
  for (int u=tid; u<1024; u+=256){ int r=u>>5, c=u&31; t[r][c]=s[(size_t)(n0+r)*512 + d0+c]; }
  __syncthreads();
  u16* d = vTA + (size_t)bh*80*2048;
  for (int u=tid; u<1024; u+=256){ int c=u>>5, r=u&31; d[(size_t)(d0+c)*2048 + n0+r]=t[r][c]; }
}

// ---------------- vsum[bh][d] = sum_n v[n][d] ----------------
__global__ __launch_bounds__(256) void k_vsum(const u16* __restrict__ vB, float* __restrict__ vsum){
  int bh=blockIdx.x; int b=bh>>3, h=bh&7;
  int tid=threadIdx.x; int d=tid&63, part=tid>>6;
  const u16* src = vB + (size_t)(b*2048 + part*512)*512 + h*64 + d;
  float s=0.f;
  for (int n=0;n<512;++n) s += bf2f(src[(size_t)n*512]);
  __shared__ float red[256];
  red[tid]=s; __syncthreads();
  if (part==0) vsum[bh*64+d]=red[d]+red[64+d]+red[128+d]+red[192+d];
}

// ---------------- per-bh sums: Csum[d] = sum_m ctxT[d][m]; Ssum = sum_m kcs[m] ----------------
__global__ __launch_bounds__(256) void k_sums(const u16* __restrict__ ctxT, const float* __restrict__ kcs,
                                              float* __restrict__ ctxsum, float* __restrict__ kcssum){
  int bh = blockIdx.x;
  int tid = threadIdx.x;
  int d = tid&63, part = tid>>6;
  const u16* src = ctxT + (size_t)bh*64*512 + (size_t)d*512 + part*128;
  float s=0.f;
  for (int m=0;m<128;m+=8){
    bf16x8 v = *(const bf16x8*)&src[m];
    #pragma unroll
    for (int j=0;j<8;++j) s += bf2f((u16)v[j]);
  }
  __shared__ float red[256];
  __shared__ float red2[256];
  red[tid]=s;
  float t=0.f;
  for (int u=tid;u<512;u+=256) t += kcs[(size_t)bh*512+u];
  red2[tid]=t;
  __syncthreads();
  if (part==0) ctxsum[bh*64+d] = red[d]+red[64+d]+red[128+d]+red[192+d];
  if (tid<64){
    float a=red2[tid]+red2[tid+64]+red2[tid+128]+red2[tid+192];
    #pragma unroll
    for (int m2=1;m2<64;m2<<=1) a += __shfl_xor(a,m2,64);
    if (tid==0) kcssum[bh]=a;
  }
}

// ---------------- GEMM m97-style: O[8192x512] = A(bf16) @ BT^T + bias ----------------
template<bool OF32>
__global__ __launch_bounds__(256) void k_gemm2(const u16* __restrict__ A,
    const u16* BT0, const u16* BT1, const u16* BT2,
    const float* b0, const float* b1, const float* b2,
    void* O0, void* O1, void* O2)
{
  int z = blockIdx.z;
  const u16* BT    = z==0?BT0:(z==1?BT1:BT2);
  const float* bias= z==0?b0 :(z==1?b1 :b2 );
  void* Ov         = z==0?O0 :(z==1?O1 :O2 );
  int bm = blockIdx.x*128, bn = blockIdx.y*64;
  __shared__ u16 sA[128*64];
  __shared__ u16 sB[64*64];
  int tid=threadIdx.x, w=tid>>6, lane=tid&63;
  int lr = lane>>3, lc = (lane&7)*8;
  f32x4 acc[8] = {};
  for (int kk=0; kk<512; kk+=64){
    __syncthreads();
    #pragma unroll
    for (int i=0;i<4;++i){
      int idx = w*4+i;
      async_lds16(&sA[idx*512], A + (size_t)(bm + idx*8 + lr)*512 + kk + lc);
    }
    #pragma unroll
    for (int i=0;i<2;++i){
      int idx = w*2+i;
      async_lds16(&sB[idx*512], BT + (size_t)(bn + idx*8 + lr)*512 + kk + lc);
    }
    __syncthreads();
    int fr = lane&15, kb=(lane>>4)*8;
    #pragma unroll
    for (int rt=0; rt<2; ++rt){
      int ar = (w*2+rt)*16 + fr;
      #pragma unroll
      for (int ct=0; ct<4; ++ct){
        int br = ct*16 + fr;
        #pragma unroll
        for (int kc=0; kc<2; ++kc){
          bf16x8 av = *(const bf16x8*)&sA[ar*64 + kc*32 + kb];
          bf16x8 bv = *(const bf16x8*)&sB[br*64 + kc*32 + kb];
          acc[rt*4+ct] = MFMA16(av,bv,acc[rt*4+ct]);
        }
      }
    }
  }
  int colg = lane&15, rowg=(lane>>4)*4;
  #pragma unroll
  for (int rt=0; rt<2; ++rt){
    #pragma unroll
    for (int ct=0; ct<4; ++ct){
      int col = bn + ct*16 + colg;
      float bv = bias[col];
      #pragma unroll
      for (int j=0;j<4;++j){
        int row = bm + (w*2+rt)*16 + rowg + j;
        if constexpr (OF32) ((float*)Ov)[(size_t)row*512 + col] = acc[rt*4+ct][j] + bv;
        else                ((u16*) Ov)[(size_t)row*512 + col] = f2bf(acc[rt*4+ct][j] + bv);
      }
    }
  }
}

// ---------------- one-shot k-feature GEMM: kpT[lbh][m][n] = exp(k.p - diag), + kmax ----------------
// grid (x = bn*64 + bm  [512], y = h-in-pass [4]); x%8 == bm%8 -> bn-sharers on one XCD.
__global__ __launch_bounds__(256) void k_feat(const u16* __restrict__ kB, const u16* __restrict__ projS,
    u16* __restrict__ kpT, u32* __restrict__ kmaxEnc, int hbase)
{
  int xx=blockIdx.x, hy=blockIdx.y;
  int bm = xx&63, bn = xx>>6;
  int h = hbase + hy;
  int b = bm>>4;
  int gbh = b*8 + h;
  int lbh = b*4 + hy;
  __shared__ __align__(16) u16 sA[128*72];    // k-hat tile; reused as sT transpose bounce (64*136<=128*72)
  __shared__ __align__(16) u16 sB[64*72];     // proj chunk
  __shared__ float diag[128];
  __shared__ float red[4];
  u16* sT = sA;
  int tid=threadIdx.x, w=tid>>6, lane=tid&63;
  int fr=lane&15, kb=(lane>>4)*8, rowg=(lane>>4)*4;
  stage64<128>(sA, kB + (size_t)(bm*128)*512 + h*64, 512, tid);
  stage64<64> (sB, projS + bn*64*64, 64, tid);
  __syncthreads();
  if (tid<128){
    float s=0.f;
    #pragma unroll
    for (int c=0;c<64;c+=8){
      bf16x8 v=*(const bf16x8*)&sA[tid*72+c];
      #pragma unroll
      for (int j=0;j<8;++j){ float f=bf2f((u16)v[j]); s+=f*f; }
    }
    diag[tid]=0.0625f*s;
  }
  f32x4 acc[8];
  float lm=-3.0e38f;
  #pragma unroll
  for (int rt=0;rt<2;++rt){
    int ar=(w*2+rt)*16+fr;
    #pragma unroll
    for (int mt=0;mt<4;++mt){
      f32x4 a={0.f,0.f,0.f,0.f};
      a=MFMA16(*(const bf16x8*)&sA[ar*72+kb],    *(const bf16x8*)&sB[(mt*16+fr)*72+kb],    a);
      a=MFMA16(*(const bf16x8*)&sA[ar*72+32+kb], *(const bf16x8*)&sB[(mt*16+fr)*72+32+kb], a);
      acc[rt*4+mt]=a;
      lm=fmaxf(lm, fmaxf(fmaxf(a[0],a[1]),fmaxf(a[2],a[3])));
    }
  }
  __syncthreads();   // sA reads done, diag visible
  // exp -> sT[m 64][n pad136], transposed bounce
  #pragma unroll
  for (int rt=0;rt<2;++rt){
    int nl=(w*2+rt)*16+rowg;
    #pragma unroll
    for (int mt=0;mt<4;++mt){
      int ml=mt*16+fr;
      s16x4 pk;
      #pragma unroll
      for (int j=0;j<4;++j) pk[j]=(short)f2bf(__expf(acc[rt*4+mt][j]-diag[nl+j]));
      *(s16x4*)&sT[ml*136+nl]=pk;
    }
  }
  #pragma unroll
  for (int m2=1;m2<64;m2<<=1) lm=fmaxf(lm,__shfl_xor(lm,m2,64));
  if (lane==0) red[w]=lm;
  __syncthreads();   // sT visible, red visible
  if (tid==0) atomicMax(&kmaxEnc[gbh], encf(fmaxf(fmaxf(red[0],red[1]),fmaxf(red[2],red[3]))));
  for (int u=tid; u<1024; u+=256){
    int r=u>>4, c=(u&15)<<3;
    *(int4*)&kpT[((size_t)lbh*512 + bn*64 + r)*2048 + (bm&15)*128 + c] = *(const int4*)&sT[r*136+c];
  }
}

// ---------------- ctx GEMM: ctxP[ks][lbh][m][80] = kpT[m][nslice] @ vTA[80][nslice]^T ----------------
// col 64 = kcs (ones row). grid flat 256: x = (ks*4+mt)*16 + lbh  -> x%8 == lbh%8 (XCD locality).
__global__ __launch_bounds__(256) void k_ctxg(const u16* __restrict__ kpT, const u16* __restrict__ vTA,
    u16* __restrict__ ctxPT, int hbase)
{
  int x=blockIdx.x;
  int lbh = x&15, km = x>>4, ks = km>>2, mt4 = km&3;
  int b = lbh>>2, hy = lbh&3;
  int gbh = b*8 + hbase + hy;
  int m0 = mt4*128;
  __shared__ __align__(16) u16 sA[128*64];
  __shared__ __align__(16) u16 sB[80*64];
  __shared__ __align__(16) u16 sO[128*80];
  int tid=threadIdx.x, w=tid>>6, lane=tid&63;
  int lr=lane>>3, lc=(lane&7)*8;
  int fr=lane&15, kb=(lane>>4)*8, rowg=(lane>>4)*4;
  const u16* Ab = kpT + (size_t)(lbh*512 + m0)*2048 + ks*512;
  const u16* Bb = vTA + (size_t)gbh*80*2048 + ks*512;
  f32x4 acc[10] = {};
  for (int kk=0; kk<512; kk+=64){
    __syncthreads();
    #pragma unroll
    for (int i=0;i<4;++i){
      int idx = w*4+i;
      async_lds16(&sA[idx*512], Ab + (size_t)(idx*8+lr)*2048 + kk + lc);
    }
    for (int c=w; c<10; c+=4){
      async_lds16(&sB[c*512], Bb + (size_t)(c*8+lr)*2048 + kk + lc);
    }
    __syncthreads();
    #pragma unroll
    for (int rt=0; rt<2; ++rt){
      int ar = (w*2+rt)*16 + fr;
      #pragma unroll
      for (int ct=0; ct<5; ++ct){
        int br = ct*16 + fr;
        #pragma unroll
        for (int kc=0; kc<2; ++kc){
          bf16x8 av = *(const bf16x8*)&sA[ar*64 + kc*32 + kb];
          bf16x8 bv = *(const bf16x8*)&sB[br*64 + kc*32 + kb];
          acc[rt*5+ct] = MFMA16(av,bv,acc[rt*5+ct]);
        }
      }
    }
  }
  __syncthreads();
  #pragma unroll
  for (int rt=0;rt<2;++rt){
    int ml=(w*2+rt)*16+rowg;
    #pragma unroll
    for (int ct=0;ct<5;++ct){
      #pragma unroll
      for (int j=0;j<4;++j) sO[(ml+j)*80 + ct*16+fr] = f2bf(acc[rt*5+ct][j]);
    }
  }
  __syncthreads();
  for (int u=tid; u<1280; u+=256){
    int r=u/10, c=(u%10)*8;
    *(int4*)&ctxPT[(((size_t)ks*16 + lbh)*512 + m0 + r)*80 + c] = *(const int4*)&sO[r*80+c];
  }
}

// ---------------- combine 4 k-split partials -> ctxT (transposed, bf16) + kcs f32 ----------------
__global__ __launch_bounds__(256) void k_comb(const u16* __restrict__ ctxPT, u16* __restrict__ ctxT,
                                              float* __restrict__ kcs, int hbase)
{
  int lbh=blockIdx.x, mblk=blockIdx.y;
  int b=lbh>>2, hy=lbh&3, gbh=b*8+hbase+hy;
  int m0=mblk*64;
  __shared__ float sTf[80*68];
  int tid=threadIdx.x;
  for (int u=tid; u<640; u+=256){
    int m=u/10, c=(u%10)*8;
    float v[8]={0.f,0.f,0.f,0.f,0.f,0.f,0.f,0.f};
    #pragma unroll
    for (int ks=0;ks<4;++ks){
      bf16x8 raw = *(const bf16x8*)&ctxPT[(((size_t)ks*16+lbh)*512 + m0+m)*80 + c];
      #pragma unroll
      for (int j=0;j<8;++j) v[j]+=bf2f((u16)raw[j]);
    }
    #pragma unroll
    for (int j=0;j<8;++j) sTf[(c+j)*68 + m] = v[j];
  }
  __syncthreads();
  for (int u=tid; u<1024; u+=256){
    int d=u>>4, m=(u&15)*4;
    u16 t[4]={f2bf(sTf[d*68+m]),f2bf(sTf[d*68+m+1]),f2bf(sTf[d*68+m+2]),f2bf(sTf[d*68+m+3])};
    *(int2*)&ctxT[((size_t)gbh*64 + d)*512 + m0 + m] = *(const int2*)t;
  }
  if (tid<64) kcs[(size_t)gbh*512 + m0 + tid] = sTf[64*68 + tid];
}

// ---------------- q features (exp-only) + PV + exact eps epilogue ----------------
// grid (8 h, 16 chunk, 4 b). sCt single-buffered -> 45.5KB LDS -> 3 blocks/CU.
__global__ __launch_bounds__(256) void k_qpout2(const u16* __restrict__ qB, const u16* __restrict__ projS,
    const float* __restrict__ kcs, const u16* __restrict__ ctxT,
    const float* __restrict__ ctxsum, const float* __restrict__ kcssum,
    const float* __restrict__ vsum, const u32* __restrict__ kmaxEnc,
    u16* __restrict__ outc)
{
  int h=blockIdx.x, chunk=blockIdx.y, b=blockIdx.z;
  int bh=b*8+h;
  int t0 = b*2048 + chunk*128;
  __shared__ u16 sP[2][64*64];
  __shared__ u16 sCt[64*64];
  __shared__ u16 qpL[128*72];
  __shared__ float sK[512];
  __shared__ float diag[128];
  int tid=threadIdx.x, w=tid>>6, lane=tid&63;
  int fr=lane&15, kb=(lane>>4)*8, rowg=(lane>>4)*4;
  bf16x8 qf[2][2];
  #pragma unroll
  for (int rt=0;rt<2;++rt)
    #pragma unroll
    for (int kc=0;kc<2;++kc)
      qf[rt][kc] = *(const bf16x8*)&qB[(size_t)(t0 + w*32 + rt*16 + fr)*512 + h*64 + kc*32 + kb];
  #pragma unroll
  for (int rt=0;rt<2;++rt){
    float s=0.f;
    #pragma unroll
    for (int kc=0;kc<2;++kc)
      #pragma unroll
      for (int j=0;j<8;++j){ float f=bf2f((u16)qf[rt][kc][j]); s+=f*f; }
    s += __shfl_xor(s,16,64); s += __shfl_xor(s,32,64);
    if (lane<16) diag[w*32 + rt*16 + fr] = 0.0625f*s;
  }
  for (int u=tid; u<512; u+=256) sK[u] = kcs[(size_t)bh*512 + u];
  const u16* gcB = ctxT + (size_t)bh*64*512;
  int lr=lane>>3, lc=(lane&7)*8;
  {
    #pragma unroll
    for (int i=0;i<2;++i){
      int idx = w*2+i;
      async_lds16(&sP[0][idx*512], projS + idx*512 + lane*8);
      async_lds16(&sCt[idx*512], gcB + (size_t)(idx*8+lr)*512 + lc);
    }
  }
  f32x4 acc2[2][4]={};
  float mx[2][4], dp[2][4], rs[2][4];
  #pragma unroll
  for (int rt=0;rt<2;++rt)
    #pragma unroll
    for (int j=0;j<4;++j){ mx[rt][j]=-3.0e38f; dp[rt][j]=0.f; rs[rt][j]=0.f; }
  __syncthreads();
  for (int mc=0; mc<8; ++mc){
    int cur = mc&1;
    if (mc>0){
      #pragma unroll
      for (int i=0;i<2;++i){
        int idx = w*2+i;
        async_lds16(&sCt[idx*512], gcB + (size_t)(idx*8+lr)*512 + mc*64 + lc);
      }
    }
    if (mc<7){
      int nxt = cur^1;
      const u16* gp = projS + (mc+1)*64*64;
      #pragma unroll
      for (int i=0;i<2;++i){
        int idx = w*2+i;
        async_lds16(&sP[nxt][idx*512], gp + idx*512 + lane*8);
      }
    }
    f32x4 facc[2][4];
    #pragma unroll
    for (int rt=0;rt<2;++rt){
      #pragma unroll
      for (int mt=0;mt<4;++mt){
        f32x4 a={0.f,0.f,0.f,0.f};
        #pragma unroll
        for (int kc=0;kc<2;++kc){
          bf16x8 bv = *(const bf16x8*)&sP[cur][(mt*16+fr)*64 + kc*32 + kb];
          a = MFMA16(qf[rt][kc], bv, a);
        }
        facc[rt][mt]=a;
      }
    }
    #pragma unroll
    for (int rt=0;rt<2;++rt){
      #pragma unroll
      for (int mt=0;mt<4;++mt){
        #pragma unroll
        for (int j=0;j<4;++j){
          int rl = w*32 + rt*16 + rowg + j;
          mx[rt][j] = fmaxf(mx[rt][j], facc[rt][mt][j]);
          float vq = __expf(facc[rt][mt][j] - diag[rl]);
          u16 us = f2bf(vq);
          qpL[rl*72 + mt*16 + fr] = us;
          float uf = bf2f(us);
          dp[rt][j] += uf*sK[mc*64 + mt*16 + fr];
          rs[rt][j] += uf;
        }
      }
    }
    __syncthreads();   // qpL + sCt(mc) ready (vmcnt drained)
    #pragma unroll
    for (int rt=0;rt<2;++rt){
      #pragma unroll
      for (int ct=0;ct<4;++ct){
        #pragma unroll
        for (int kc=0;kc<2;++kc){
          bf16x8 av = *(const bf16x8*)&qpL[(w*32+rt*16+fr)*72 + kc*32 + kb];
          bf16x8 bv = *(const bf16x8*)&sCt[(ct*16+fr)*64 + kc*32 + kb];
          acc2[rt][ct] = MFMA16(av,bv,acc2[rt][ct]);
        }
      }
    }
    __syncthreads();   // qpL/sCt free for next chunk
  }
  #pragma unroll
  for (int rt=0;rt<2;++rt){
    #pragma unroll
    for (int j=0;j<4;++j){
      #pragma unroll
      for (int s=1;s<16;s<<=1){
        dp[rt][j] += __shfl_xor(dp[rt][j],s,64);
        rs[rt][j] += __shfl_xor(rs[rt][j],s,64);
        mx[rt][j]  = fmaxf(mx[rt][j], __shfl_xor(mx[rt][j],s,64));
      }
    }
  }
  float mk  = decf(kmaxEnc[bh]);
  float emk = __expf(mk);
  float Ssum = kcssum[bh];
  const float eps=1e-4f;
  float emq[2][4];
  #pragma unroll
  for (int rt=0;rt<2;++rt)
    #pragma unroll
    for (int j=0;j<4;++j) emq[rt][j]=__expf(mx[rt][j]);
  #pragma unroll
  for (int rt=0;rt<2;++rt){
    #pragma unroll
    for (int ct=0;ct<4;++ct){
      int d = ct*16 + fr;
      float cs = ctxsum[bh*64 + d];
      float vs = vsum[bh*64 + d];
      #pragma unroll
      for (int j=0;j<4;++j){
        float eq = emq[rt][j];
        float numer = acc2[rt][ct][j] + eps*(emk*vs*rs[rt][j] + eq*cs + eps*eq*emk*512.0f*vs);
        float den   = dp[rt][j]       + eps*(emk*2048.0f*rs[rt][j] + eq*Ssum + eps*eq*emk*512.0f*2048.0f);
        int row = t0 + w*32 + rt*16 + rowg + j;
        outc[(size_t)row*512 + h*64 + d] = f2bf(numer/den);
      }
    }
  }
}

extern "C" void kernel_launch(void* const* d_in, const int* in_sizes, int n_in,
                              void* d_out, int out_size, void* d_ws, size_t ws_size,
                              hipStream_t stream)
{
  (void)in_sizes; (void)n_in; (void)out_size; (void)ws_size;
  const float* x    = (const float*)d_in[0];
  const float* Wq   = (const float*)d_in[1];
  const float* bq   = (const float*)d_in[2];
  const float* Wk   = (const float*)d_in[3];
  const float* bk   = (const float*)d_in[4];
  const float* Wv   = (const float*)d_in[5];
  const float* bv   = (const float*)d_in[6];
  const float* Wo   = (const float*)d_in[7];
  const float* bo   = (const float*)d_in[8];
  const float* proj = (const float*)d_in[9];

  char* w = (char*)d_ws;
  size_t off=0;
  auto alloc=[&](size_t bytes)->char*{ char* p=w+off; off=(off+bytes+255)&~(size_t)255; return p; };
  u16*  xb   = (u16*)alloc(8192ull*512*2);
  u16*  qB   = (u16*)alloc(8192ull*512*2);
  u16*  kBf  = (u16*)alloc(8192ull*512*2);
  u16*  vB   = (u16*)alloc(8192ull*512*2);
  u16*  vTA  = (u16*)alloc(32ull*80*2048*2);
  u16*  WqT  = (u16*)alloc(512ull*512*2);
  u16*  WkT  = (u16*)alloc(512ull*512*2);
  u16*  WvT  = (u16*)alloc(512ull*512*2);
  u16*  WoT  = (u16*)alloc(512ull*512*2);
  u16*  projS= (u16*)alloc(512ull*64*2);
  u16*  kpT  = (u16*)alloc(16ull*512*2048*2);      // per head-half pass
  u16*  ctxPT= (u16*)alloc(4ull*16*512*80*2);      // 4 k-splits, bf16
  u16*  ctxT = (u16*)alloc(32ull*64*512*2);
  float* kcs = (float*)alloc(32ull*512*4);
  u32*  kmx  = (u32*)alloc(256);
  float* ctxs= (float*)alloc(32ull*64*4);
  float* kcss= (float*)alloc(32ull*4);
  float* vsm = (float*)alloc(32ull*64*4);
  u16*  outc = kBf;  // kBf dead after k_feat passes; reuse

  dim3 TB(256);
  k_init<<<dim3(1024),TB,0,stream>>>(kmx,projS,vTA,proj,x,xb);
  k_trw<<<dim3(16,16,4),TB,0,stream>>>(Wq,Wk,Wv,Wo, WqT,WkT,WvT,WoT);
  k_gemm2<false><<<dim3(64,8,3),TB,0,stream>>>(xb, WqT,WkT,WvT, bq,bk,bv, qB,kBf,vB);
  k_trv<<<dim3(2,64,32),TB,0,stream>>>(vB, vTA);
  k_vsum<<<dim3(32),TB,0,stream>>>(vB, vsm);
  for (int pass=0; pass<2; ++pass){
    int hbase = pass*4;
    k_feat<<<dim3(512,4),TB,0,stream>>>(kBf, projS, kpT, kmx, hbase);
    k_ctxg<<<dim3(256),TB,0,stream>>>(kpT, vTA, ctxPT, hbase);
    k_comb<<<dim3(16,8),TB,0,stream>>>(ctxPT, ctxT, kcs, hbase);
  }
  k_sums<<<dim3(32),TB,0,stream>>>(ctxT, kcs, ctxs, kcss);
  k_qpout2<<<dim3(8,16,4),TB,0,stream>>>(qB, projS, kcs, ctxT, ctxs, kcss, vsm, kmx, outc);
  k_gemm2<true><<<dim3(64,8,1),TB,0,stream>>>(outc, WoT,WoT,WoT, bo,bo,bo,
                                              d_out,d_out,d_out);
}

// Round 8
// 163.586 us; speedup vs baseline: 1.0872x; 1.0872x over previous
//
#include <hip/hip_runtime.h>

typedef unsigned short u16;
typedef unsigned int   u32;
typedef __attribute__((ext_vector_type(8))) short bf16x8;
typedef __attribute__((ext_vector_type(4))) short s16x4;
typedef __attribute__((ext_vector_type(4))) float f32x4;

#define MFMA16(a,b,c) __builtin_amdgcn_mfma_f32_16x16x32_bf16((a),(b),(c),0,0,0)

// soft barriers: raw s_barrier + counted waits (no vmcnt drain unless counted)
#define SOFT_BAR_LG() do{ asm volatile("s_waitcnt lgkmcnt(0)" ::: "memory"); \
  __builtin_amdgcn_s_barrier(); __builtin_amdgcn_sched_barrier(0); }while(0)
#define SOFT_BAR_VM(N) do{ asm volatile("s_waitcnt vmcnt(" #N ") lgkmcnt(0)" ::: "memory"); \
  __builtin_amdgcn_s_barrier(); __builtin_amdgcn_sched_barrier(0); }while(0)

__device__ __forceinline__ float bf2f(u16 u){ return __uint_as_float(((u32)u)<<16); }
__device__ __forceinline__ u16 f2bf(float f){
  u32 u = __float_as_uint(f);
  return (u16)((u + 0x7fffu + ((u>>16)&1u)) >> 16);
}
__device__ __forceinline__ u32 encf(float f){ u32 u=__float_as_uint(f); return (u&0x80000000u)? ~u : (u|0x80000000u); }
__device__ __forceinline__ float decf(u32 u){ return (u&0x80000000u)? __uint_as_float(u&0x7fffffffu) : __uint_as_float(~u); }

// async global->LDS, 16B per lane, LDS dest = wave-uniform base + lane*16
__device__ __forceinline__ void async_lds16(u16* lds, const u16* g){
  __builtin_amdgcn_global_load_lds((const __attribute__((address_space(1))) void*)g,
                                   (__attribute__((address_space(3))) void*)lds,
                                   16, 0, 0);
}

// stage ROWS x 64 bf16 from global (srcStride elems) into LDS padded to 72/row
template<int ROWS>
__device__ __forceinline__ void stage64(u16* dst, const u16* src, int srcStride, int tid){
  #pragma unroll
  for (int u=tid; u<ROWS*8; u+=256){
    int r=u>>3, c=(u&7)<<3;
    *(int4*)&dst[r*72+c] = *(const int4*)&src[(size_t)r*srcStride + c];
  }
}

// ---------------- init: zero kmax, projS = dn*proj (bf16), x -> bf16 ----------------
__global__ void k_init(u32* kmaxEnc, u16* projS,
                       const float* __restrict__ proj, const float* __restrict__ x, u16* __restrict__ xb){
  int i = blockIdx.x*blockDim.x + threadIdx.x;
  int st = gridDim.x*blockDim.x;
  for (int j=i; j<32; j+=st) kmaxEnc[j]=0u;
  const float dn = 0.35355339059327373f; // 64^-0.25
  for (int j=i; j<512*64; j+=st) projS[j] = f2bf(dn*proj[j]);
  for (int j=i; j<524288; j+=st){
    float4 a = *(const float4*)&x[(size_t)j*8];
    float4 b = *(const float4*)&x[(size_t)j*8+4];
    u16 tmp[8] = {f2bf(a.x),f2bf(a.y),f2bf(a.z),f2bf(a.w),
                  f2bf(b.x),f2bf(b.y),f2bf(b.z),f2bf(b.w)};
    *(int4*)&xb[(size_t)j*8] = *(const int4*)tmp;
  }
}

// ---------------- fp32 512x512 -> bf16 transpose, batched over 4 weights ----------------
__global__ __launch_bounds__(256) void k_trw(const float* s0, const float* s1, const float* s2, const float* s3,
                                             u16* d0, u16* d1, u16* d2, u16* d3){
  int z = blockIdx.z;
  const float* src = z==0?s0:(z==1?s1:(z==2?s2:s3));
  u16* dst         = z==0?d0:(z==1?d1:(z==2?d2:d3));
  __shared__ u16 t[32][34];
  int c0=blockIdx.x*32, r0=blockIdx.y*32;
  int tid=threadIdx.x;
  for (int u=tid; u<1024; u+=256){ int r=u>>5, c=u&31; t[r][c]=f2bf(src[(size_t)(r0+r)*512 + c0+c]); }
  __syncthreads();
  for (int u=tid; u<1024; u+=256){ int c=u>>5, r=u&31; dst[(size_t)(c0+c)*512 + r0+r]=t[r][c]; }
}

// ---------------- v (per b,h 2048x64 slice of [t][512]) -> vT[bh][64][2048] ----------------
__global__ __launch_bounds__(256) void k_trv(const u16* __restrict__ v, u16* __restrict__ vT){
  int bh = blockIdx.z; int b=bh>>3, h=bh&7;
  int d0 = blockIdx.x*32, n0 = blockIdx.y*32;
  __shared__ u16 t[32][34];
  int tid=threadIdx.x;
  const u16* s = v + (size_t)(b*2048)*512 + h*64;
  for (int u=tid; u<1024; u+=256){ int r=u>>5, c=u&31; t[r][c]=s[(size_t)(n0+r)*512 + d0+c]; }
  __syncthreads();
  u16* d = vT + (size_t)bh*64*2048;
  for (int u=tid; u<1024; u+=256){ int c=u>>5, r=u&31; d[(size_t)(d0+c)*2048 + n0+r]=t[r][c]; }
}

// ---------------- vsum[bh][d] = sum_n v[n][d] ----------------
__global__ __launch_bounds__(256) void k_vsum(const u16* __restrict__ vB, float* __restrict__ vsum){
  int bh=blockIdx.x; int b=bh>>3, h=bh&7;
  int tid=threadIdx.x; int d=tid&63, part=tid>>6;
  const u16* src = vB + (size_t)(b*2048 + part*512)*512 + h*64 + d;
  float s=0.f;
  for (int n=0;n<512;++n) s += bf2f(src[(size_t)n*512]);
  __shared__ float red[256];
  red[tid]=s; __syncthreads();
  if (part==0) vsum[bh*64+d]=red[d]+red[64+d]+red[128+d]+red[192+d];
}

// ---------------- diagK[bh][n] = 0.0625 * sum_k k[n][k]^2 ----------------
__global__ __launch_bounds__(256) void k_kdiag(const u16* __restrict__ kB, float* __restrict__ diagK){
  int bh=blockIdx.x, seg=blockIdx.y;
  int b=bh>>3, h=bh&7;
  int tid=threadIdx.x;
  int part=tid&7;
  const u16* base = kB + (size_t)(b*2048 + seg*256)*512 + h*64 + part*8;
  for (int n0=0; n0<256; n0+=32){
    int n = n0 + (tid>>3);
    bf16x8 v = *(const bf16x8*)&base[(size_t)n*512];
    float sq=0.f;
    #pragma unroll
    for (int j=0;j<8;++j){ float f=bf2f((u16)v[j]); sq+=f*f; }
    sq += __shfl_xor(sq,1,64); sq += __shfl_xor(sq,2,64); sq += __shfl_xor(sq,4,64);
    if (part==0) diagK[(size_t)bh*2048 + seg*256 + n] = 0.0625f*sq;
  }
}

// ---------------- per-bh sums: Csum[d] = sum_m ctxT[d][m]; Ssum = sum_m kcs[m] ----------------
__global__ __launch_bounds__(256) void k_sums(const u16* __restrict__ ctxT, const float* __restrict__ kcs,
                                              float* __restrict__ ctxsum, float* __restrict__ kcssum){
  int bh = blockIdx.x;
  int tid = threadIdx.x;
  int d = tid&63, part = tid>>6;
  const u16* src = ctxT + (size_t)bh*64*512 + (size_t)d*512 + part*128;
  float s=0.f;
  for (int m=0;m<128;m+=8){
    bf16x8 v = *(const bf16x8*)&src[m];
    #pragma unroll
    for (int j=0;j<8;++j) s += bf2f((u16)v[j]);
  }
  __shared__ float red[256];
  __shared__ float red2[256];
  red[tid]=s;
  float t=0.f;
  for (int u=tid;u<512;u+=256) t += kcs[(size_t)bh*512+u];
  red2[tid]=t;
  __syncthreads();
  if (part==0) ctxsum[bh*64+d] = red[d]+red[64+d]+red[128+d]+red[192+d];
  if (tid<64){
    float a=red2[tid]+red2[tid+64]+red2[tid+128]+red2[tid+192];
    #pragma unroll
    for (int m2=1;m2<64;m2<<=1) a += __shfl_xor(a,m2,64);
    if (tid==0) kcssum[bh]=a;
  }
}

// ---------------- GEMM, 2-deep async pipeline (T3/T4): O = A @ BT^T + bias ----------------
template<bool OF32>
__global__ __launch_bounds__(256) void k_gemm2(const u16* __restrict__ A,
    const u16* BT0, const u16* BT1, const u16* BT2,
    const float* b0, const float* b1, const float* b2,
    void* O0, void* O1, void* O2)
{
  int z = blockIdx.z;
  const u16* BT    = z==0?BT0:(z==1?BT1:BT2);
  const float* bias= z==0?b0 :(z==1?b1 :b2 );
  void* Ov         = z==0?O0 :(z==1?O1 :O2 );
  int bm = blockIdx.x*128, bn = blockIdx.y*64;
  __shared__ u16 sA[2][128*64];
  __shared__ u16 sB[2][64*64];
  int tid=threadIdx.x, w=tid>>6, lane=tid&63;
  int lr = lane>>3, lc = (lane&7)*8;
  f32x4 acc[8] = {};
  // stage K-chunk koff into buffer bf (6 asyncs per wave)
  auto stage=[&](int bf, int koff){
    #pragma unroll
    for (int i=0;i<4;++i){
      int idx = w*4+i;
      async_lds16(&sA[bf][idx*512], A + (size_t)(bm + idx*8 + lr)*512 + koff + lc);
    }
    #pragma unroll
    for (int i=0;i<2;++i){
      int idx = w*2+i;
      async_lds16(&sB[bf][idx*512], BT + (size_t)(bn + idx*8 + lr)*512 + koff + lc);
    }
  };
  stage(0, 0);
  int fr = lane&15, kb=(lane>>4)*8;
  for (int kk=0; kk<8; ++kk){
    int cur = kk&1;
    if (kk<7) stage(cur^1, (kk+1)*64);
    // retire the stage for buf[cur] (issued last iter; 6 newest allowed in flight), publish via barrier
    if (kk<7) { SOFT_BAR_VM(6); } else { SOFT_BAR_VM(0); }
    #pragma unroll
    for (int rt=0; rt<2; ++rt){
      int ar = (w*2+rt)*16 + fr;
      #pragma unroll
      for (int ct=0; ct<4; ++ct){
        int br = ct*16 + fr;
        #pragma unroll
        for (int kc=0; kc<2; ++kc){
          bf16x8 av = *(const bf16x8*)&sA[cur][ar*64 + kc*32 + kb];
          bf16x8 bv = *(const bf16x8*)&sB[cur][br*64 + kc*32 + kb];
          acc[rt*4+ct] = MFMA16(av,bv,acc[rt*4+ct]);
        }
      }
    }
    SOFT_BAR_LG();   // reads retired before next stage overwrites this buffer
  }
  int colg = lane&15, rowg=(lane>>4)*4;
  #pragma unroll
  for (int rt=0; rt<2; ++rt){
    #pragma unroll
    for (int ct=0; ct<4; ++ct){
      int col = bn + ct*16 + colg;
      float bv = bias[col];
      #pragma unroll
      for (int j=0;j<4;++j){
        int row = bm + (w*2+rt)*16 + rowg + j;
        if constexpr (OF32) ((float*)Ov)[(size_t)row*512 + col] = acc[rt*4+ct][j] + bv;
        else                ((u16*) Ov)[(size_t)row*512 + col] = f2bf(acc[rt*4+ct][j] + bv);
      }
    }
  }
}

// ---------------- k features (exp-only) + half-n ctx partial + S partial + mk ----------------
// grid (8 h, 16 = s*8+mblk, 4 b). Reg-staged prefetch survives soft (lgkm-only) barriers.
__global__ __launch_bounds__(256) void k_kpctx3(const u16* __restrict__ kB, const u16* __restrict__ projS,
    const u16* __restrict__ vT, const float* __restrict__ diagK,
    float* __restrict__ ctxPT, float* __restrict__ kcsP, u32* __restrict__ kmaxEnc)
{
  int h=blockIdx.x, y=blockIdx.y, b=blockIdx.z;
  int mblk = y&7, s = y>>3;
  int bh=b*8+h;
  int m0 = mblk*64;
  __shared__ __align__(16) u16 sK[128*72];
  __shared__ __align__(16) u16 sV[64*136];
  __shared__ __align__(16) u16 sP[64*72];
  __shared__ __align__(16) u16 sT[64*136];
  __shared__ float sDg[128];
  __shared__ float red[4];
  int tid=threadIdx.x, w=tid>>6, lane=tid&63;
  int fr=lane&15, kb=(lane>>4)*8, rowg=(lane>>4)*4;
  stage64<64>(sP, projS + m0*64, 64, tid);
  f32x4 accc[4]={};
  float sS=0.f;
  float lm=-3.0e38f;
  const u16* gK = kB + (size_t)(b*2048 + s*1024)*512 + h*64;
  const u16* gV = vT + (size_t)bh*64*2048 + s*1024;
  const float* gD = diagK + (size_t)bh*2048 + s*1024;
  int4 pK[4], pV[4]; float4 pD={0.f,0.f,0.f,0.f};
  #pragma unroll
  for (int i=0;i<4;++i){ int u=tid+i*256; int r=u>>3,c=(u&7)<<3; pK[i]=*(const int4*)&gK[(size_t)r*512 + c]; }
  #pragma unroll
  for (int i=0;i<4;++i){ int u=tid+i*256; int r=u>>4,c=(u&15)<<3; pV[i]=*(const int4*)&gV[(size_t)r*2048 + c]; }
  if (tid<32) pD = *(const float4*)&gD[tid*4];
  for (int nc=0; nc<8; ++nc){
    // stage regs -> padded LDS (compiler waits the reg loads here, counted, no drain)
    #pragma unroll
    for (int i=0;i<4;++i){ int u=tid+i*256; int r=u>>3,c=(u&7)<<3; *(int4*)&sK[r*72+c]=pK[i]; }
    #pragma unroll
    for (int i=0;i<4;++i){ int u=tid+i*256; int r=u>>4,c=(u&15)<<3; *(int4*)&sV[r*136+c]=pV[i]; }
    if (tid<32) *(float4*)&sDg[tid*4] = pD;
    SOFT_BAR_LG();
    // prefetch next chunk (in flight across all barriers, used next iteration)
    if (nc<7){
      #pragma unroll
      for (int i=0;i<4;++i){ int u=tid+i*256; int r=u>>3,c=(u&7)<<3; pK[i]=*(const int4*)&gK[(size_t)((nc+1)*128+r)*512 + c]; }
      #pragma unroll
      for (int i=0;i<4;++i){ int u=tid+i*256; int r=u>>4,c=(u&15)<<3; pV[i]=*(const int4*)&gV[(size_t)r*2048 + (nc+1)*128 + c]; }
      if (tid<32) pD = *(const float4*)&gD[(nc+1)*128 + tid*4];
    }
    // feature MFMA: dd[128 n][64 m]
    f32x4 facc[2][4];
    #pragma unroll
    for (int rt=0;rt<2;++rt){
      int ar=(w*2+rt)*16+fr;
      #pragma unroll
      for (int mt=0;mt<4;++mt){
        f32x4 a={0.f,0.f,0.f,0.f};
        a=MFMA16(*(const bf16x8*)&sK[ar*72+kb],    *(const bf16x8*)&sP[(mt*16+fr)*72+kb],    a);
        a=MFMA16(*(const bf16x8*)&sK[ar*72+32+kb], *(const bf16x8*)&sP[(mt*16+fr)*72+32+kb], a);
        facc[rt][mt]=a;
        lm=fmaxf(lm, fmaxf(fmaxf(a[0],a[1]),fmaxf(a[2],a[3])));
      }
    }
    // exp -> sT[m][n]
    #pragma unroll
    for (int rt=0;rt<2;++rt){
      int nl=(w*2+rt)*16+rowg;
      #pragma unroll
      for (int mt=0;mt<4;++mt){
        int ml=mt*16+fr;
        s16x4 pk;
        #pragma unroll
        for (int j=0;j<4;++j) pk[j]=(short)f2bf(__expf(facc[rt][mt][j]-sDg[nl+j]));
        *(s16x4*)&sT[ml*136+nl]=pk;
      }
    }
    SOFT_BAR_LG();
    // PV MFMA + S partial
    int am=w*16+fr;
    #pragma unroll
    for (int ct=0;ct<4;++ct){
      #pragma unroll
      for (int ks=0;ks<4;++ks){
        accc[ct]=MFMA16(*(const bf16x8*)&sT[am*136+ks*32+kb],
                        *(const bf16x8*)&sV[(ct*16+fr)*136+ks*32+kb], accc[ct]);
      }
    }
    {
      int m=tid>>2, q=tid&3;
      #pragma unroll
      for (int n8=0;n8<4;++n8){
        bf16x8 v=*(const bf16x8*)&sT[m*136+q*32+n8*8];
        #pragma unroll
        for (int j=0;j<8;++j) sS += bf2f((u16)v[j]);
      }
    }
    SOFT_BAR_LG();
  }
  // S partial store
  {
    int m=tid>>2, q=tid&3;
    float t=sS;
    t += __shfl_xor(t,1,64); t += __shfl_xor(t,2,64);
    if (q==0) kcsP[(size_t)(s*32+bh)*512 + m0 + m] = t;
  }
  // mk
  #pragma unroll
  for (int m2=1;m2<64;m2<<=1) lm=fmaxf(lm,__shfl_xor(lm,m2,64));
  if (lane==0) red[w]=lm;
  __syncthreads();
  if (tid==0) atomicMax(&kmaxEnc[bh], encf(fmaxf(fmaxf(red[0],red[1]),fmaxf(red[2],red[3]))));
  // ctx partial f32, transposed [d][m] via LDS bounce (reuse sT as float[64][68])
  float* sTf = (float*)sT;
  int mloc = w*16+rowg;
  #pragma unroll
  for (int ct=0;ct<4;++ct){
    #pragma unroll
    for (int j=0;j<4;++j) sTf[(ct*16+fr)*68 + mloc + j] = accc[ct][j];
  }
  __syncthreads();
  for (int u=tid; u<1024; u+=256){
    int r=u>>4, c=(u&15)*4;
    *(float4*)&ctxPT[((size_t)(s*32+bh)*64 + r)*512 + m0 + c] = *(const float4*)&sTf[r*68+c];
  }
}

// ---------------- combine split-n partials: ctxT bf16 + kcs ----------------
__global__ __launch_bounds__(256) void k_comb(const float* __restrict__ ctxPT, u16* __restrict__ ctxT,
                                              const float* __restrict__ kcsP, float* __restrict__ kcs){
  int bh=blockIdx.x, dblk=blockIdx.y;
  int tid=threadIdx.x;
  int d0=dblk*8;
  const float* p0 = ctxPT + ((size_t)bh*64 + d0)*512;
  const float* p1 = ctxPT + ((size_t)(32+bh)*64 + d0)*512;
  u16* o = ctxT + ((size_t)bh*64 + d0)*512;
  for (int u=tid; u<1024; u+=256){
    int r=u>>7, c=(u&127)*4;
    float4 a=*(const float4*)&p0[(size_t)r*512+c];
    float4 bq=*(const float4*)&p1[(size_t)r*512+c];
    u16 t[4]={f2bf(a.x+bq.x),f2bf(a.y+bq.y),f2bf(a.z+bq.z),f2bf(a.w+bq.w)};
    *(int2*)&o[(size_t)r*512+c] = *(const int2*)t;
  }
  if (dblk==0){
    for (int u=tid; u<512; u+=256)
      kcs[(size_t)bh*512+u] = kcsP[(size_t)bh*512+u] + kcsP[(size_t)(32+bh)*512+u];
  }
}

// ---------------- q features (exp-only) + PV + exact eps epilogue, soft-barrier schedule ----------------
// grid (8 h, 16 chunk, 4 b). qpL is wave-private (rows [w*32,w*32+32)): no barrier between exp and PV.
__global__ __launch_bounds__(256) void k_qpout2(const u16* __restrict__ qB, const u16* __restrict__ projS,
    const float* __restrict__ kcs, const u16* __restrict__ ctxT,
    const float* __restrict__ ctxsum, const float* __restrict__ kcssum,
    const float* __restrict__ vsum, const u32* __restrict__ kmaxEnc,
    u16* __restrict__ outc)
{
  int h=blockIdx.x, chunk=blockIdx.y, b=blockIdx.z;
  int bh=b*8+h;
  int t0 = b*2048 + chunk*128;
  __shared__ u16 sP[2][64*64];
  __shared__ u16 sCt[64*64];
  __shared__ u16 qpL[128*72];
  __shared__ float sK[512];
  __shared__ float diag[128];
  int tid=threadIdx.x, w=tid>>6, lane=tid&63;
  int fr=lane&15, kb=(lane>>4)*8, rowg=(lane>>4)*4;
  int lr=lane>>3, lc=(lane&7)*8;
  bf16x8 qf[2][2];
  #pragma unroll
  for (int rt=0;rt<2;++rt)
    #pragma unroll
    for (int kc=0;kc<2;++kc)
      qf[rt][kc] = *(const bf16x8*)&qB[(size_t)(t0 + w*32 + rt*16 + fr)*512 + h*64 + kc*32 + kb];
  #pragma unroll
  for (int rt=0;rt<2;++rt){
    float s=0.f;
    #pragma unroll
    for (int kc=0;kc<2;++kc)
      #pragma unroll
      for (int j=0;j<8;++j){ float f=bf2f((u16)qf[rt][kc][j]); s+=f*f; }
    s += __shfl_xor(s,16,64); s += __shfl_xor(s,32,64);
    if (lane<16) diag[w*32 + rt*16 + fr] = 0.0625f*s;
  }
  for (int u=tid; u<512; u+=256) sK[u] = kcs[(size_t)bh*512 + u];
  const u16* gcB = ctxT + (size_t)bh*64*512;
  // prologue: stage sP(0); one-time full drain + barrier
  #pragma unroll
  for (int i=0;i<2;++i){
    int idx = w*2+i;
    async_lds16(&sP[0][idx*512], projS + idx*512 + lane*8);
  }
  f32x4 acc2[2][4]={};
  float mx[2][4], dp[2][4], rs[2][4];
  #pragma unroll
  for (int rt=0;rt<2;++rt)
    #pragma unroll
    for (int j=0;j<4;++j){ mx[rt][j]=-3.0e38f; dp[rt][j]=0.f; rs[rt][j]=0.f; }
  SOFT_BAR_VM(0);
  for (int mc=0; mc<8; ++mc){
    int cur = mc&1;
    // A: issue sCt(mc) then (if any) sP(mc+1)
    #pragma unroll
    for (int i=0;i<2;++i){
      int idx = w*2+i;
      async_lds16(&sCt[idx*512], gcB + (size_t)(idx*8+lr)*512 + mc*64 + lc);
    }
    if (mc<7){
      const u16* gp = projS + (mc+1)*64*64;
      #pragma unroll
      for (int i=0;i<2;++i){
        int idx = w*2+i;
        async_lds16(&sP[cur^1][idx*512], gp + idx*512 + lane*8);
      }
    }
    // B: feature MFMA on sP[cur] (retired+published at previous barrier)
    f32x4 facc[2][4];
    #pragma unroll
    for (int rt=0;rt<2;++rt){
      #pragma unroll
      for (int mt=0;mt<4;++mt){
        f32x4 a={0.f,0.f,0.f,0.f};
        #pragma unroll
        for (int kc=0;kc<2;++kc){
          bf16x8 bv = *(const bf16x8*)&sP[cur][(mt*16+fr)*64 + kc*32 + kb];
          a = MFMA16(qf[rt][kc], bv, a);
        }
        facc[rt][mt]=a;
      }
    }
    // exp -> qpL (wave-private rows), dp/rs/mx
    #pragma unroll
    for (int rt=0;rt<2;++rt){
      #pragma unroll
      for (int mt=0;mt<4;++mt){
        #pragma unroll
        for (int j=0;j<4;++j){
          int rl = w*32 + rt*16 + rowg + j;
          mx[rt][j] = fmaxf(mx[rt][j], facc[rt][mt][j]);
          float vq = __expf(facc[rt][mt][j] - diag[rl]);
          u16 us = f2bf(vq);
          qpL[rl*72 + mt*16 + fr] = us;
          float uf = bf2f(us);
          dp[rt][j] += uf*sK[mc*64 + mt*16 + fr];
          rs[rt][j] += uf;
        }
      }
    }
    // C: retire sCt (keep sP(mc+1) in flight), publish
    if (mc<7) { SOFT_BAR_VM(2); } else { SOFT_BAR_VM(0); }
    // D: PV on qpL (same wave) + sCt
    #pragma unroll
    for (int rt=0;rt<2;++rt){
      #pragma unroll
      for (int ct=0;ct<4;++ct){
        #pragma unroll
        for (int kc=0;kc<2;++kc){
          bf16x8 av = *(const bf16x8*)&qpL[(w*32+rt*16+fr)*72 + kc*32 + kb];
          bf16x8 bv = *(const bf16x8*)&sCt[(ct*16+fr)*64 + kc*32 + kb];
          acc2[rt][ct] = MFMA16(av,bv,acc2[rt][ct]);
        }
      }
    }
    // E: retire sP(mc+1) + publish; protects sCt overwrite next chunk
    if (mc<7) { SOFT_BAR_VM(0); }
  }
  #pragma unroll
  for (int rt=0;rt<2;++rt){
    #pragma unroll
    for (int j=0;j<4;++j){
      #pragma unroll
      for (int s=1;s<16;s<<=1){
        dp[rt][j] += __shfl_xor(dp[rt][j],s,64);
        rs[rt][j] += __shfl_xor(rs[rt][j],s,64);
        mx[rt][j]  = fmaxf(mx[rt][j], __shfl_xor(mx[rt][j],s,64));
      }
    }
  }
  float mk  = decf(kmaxEnc[bh]);
  float emk = __expf(mk);
  float Ssum = kcssum[bh];
  const float eps=1e-4f;
  float emq[2][4];
  #pragma unroll
  for (int rt=0;rt<2;++rt)
    #pragma unroll
    for (int j=0;j<4;++j) emq[rt][j]=__expf(mx[rt][j]);
  #pragma unroll
  for (int rt=0;rt<2;++rt){
    #pragma unroll
    for (int ct=0;ct<4;++ct){
      int d = ct*16 + fr;
      float cs = ctxsum[bh*64 + d];
      float vs = vsum[bh*64 + d];
      #pragma unroll
      for (int j=0;j<4;++j){
        float eq = emq[rt][j];
        float numer = acc2[rt][ct][j] + eps*(emk*vs*rs[rt][j] + eq*cs + eps*eq*emk*512.0f*vs);
        float den   = dp[rt][j]       + eps*(emk*2048.0f*rs[rt][j] + eq*Ssum + eps*eq*emk*512.0f*2048.0f);
        int row = t0 + w*32 + rt*16 + rowg + j;
        outc[(size_t)row*512 + h*64 + d] = f2bf(numer/den);
      }
    }
  }
}

extern "C" void kernel_launch(void* const* d_in, const int* in_sizes, int n_in,
                              void* d_out, int out_size, void* d_ws, size_t ws_size,
                              hipStream_t stream)
{
  (void)in_sizes; (void)n_in; (void)out_size; (void)ws_size;
  const float* x    = (const float*)d_in[0];
  const float* Wq   = (const float*)d_in[1];
  const float* bq   = (const float*)d_in[2];
  const float* Wk   = (const float*)d_in[3];
  const float* bk   = (const float*)d_in[4];
  const float* Wv   = (const float*)d_in[5];
  const float* bv   = (const float*)d_in[6];
  const float* Wo   = (const float*)d_in[7];
  const float* bo   = (const float*)d_in[8];
  const float* proj = (const float*)d_in[9];

  char* w = (char*)d_ws;
  size_t off=0;
  auto alloc=[&](size_t bytes)->char*{ char* p=w+off; off=(off+bytes+255)&~(size_t)255; return p; };
  u16*  xb   = (u16*)alloc(8192ull*512*2);
  u16*  qB   = (u16*)alloc(8192ull*512*2);
  u16*  kBf  = (u16*)alloc(8192ull*512*2);
  u16*  vB   = (u16*)alloc(8192ull*512*2);
  u16*  vT   = (u16*)alloc(32ull*64*2048*2);
  u16*  WqT  = (u16*)alloc(512ull*512*2);
  u16*  WkT  = (u16*)alloc(512ull*512*2);
  u16*  WvT  = (u16*)alloc(512ull*512*2);
  u16*  WoT  = (u16*)alloc(512ull*512*2);
  u16*  projS= (u16*)alloc(512ull*64*2);
  u16*  ctxT = (u16*)alloc(32ull*64*512*2);
  float* ctxPT=(float*)alloc(2ull*32*64*512*4);
  float* kcs = (float*)alloc(32ull*512*4);
  float* kcsP= (float*)alloc(2ull*32*512*4);
  float* diagK=(float*)alloc(32ull*2048*4);
  u32*  kmx  = (u32*)alloc(256);
  float* ctxs= (float*)alloc(32ull*64*4);
  float* kcss= (float*)alloc(32ull*4);
  float* vsm = (float*)alloc(32ull*64*4);
  u16*  outc = kBf;  // kBf dead after k_kpctx3; reuse

  dim3 TB(256);
  k_init<<<dim3(256),TB,0,stream>>>(kmx,projS,proj,x,xb);
  k_trw<<<dim3(16,16,4),TB,0,stream>>>(Wq,Wk,Wv,Wo, WqT,WkT,WvT,WoT);
  k_gemm2<false><<<dim3(64,8,3),TB,0,stream>>>(xb, WqT,WkT,WvT, bq,bk,bv, qB,kBf,vB);
  k_trv<<<dim3(2,64,32),TB,0,stream>>>(vB, vT);
  k_vsum<<<dim3(32),TB,0,stream>>>(vB, vsm);
  k_kdiag<<<dim3(32,8),TB,0,stream>>>(kBf, diagK);
  k_kpctx3<<<dim3(8,16,4),TB,0,stream>>>(kBf, projS, vT, diagK, ctxPT, kcsP, kmx);
  k_comb<<<dim3(32,8),TB,0,stream>>>(ctxPT, ctxT, kcsP, kcs);
  k_sums<<<dim3(32),TB,0,stream>>>(ctxT, kcs, ctxs, kcss);
  k_qpout2<<<dim3(8,16,4),TB,0,stream>>>(qB, projS, kcs, ctxT, ctxs, kcss, vsm, kmx, outc);
  k_gemm2<true><<<dim3(64,8,1),TB,0,stream>>>(outc, WoT,WoT,WoT, bo,bo,bo,
                                              d_out,d_out,d_out);
}

// Round 9
// 158.777 us; speedup vs baseline: 1.1201x; 1.0303x over previous
//
#include <hip/hip_runtime.h>

typedef unsigned short u16;
typedef unsigned int   u32;
typedef __attribute__((ext_vector_type(8))) short bf16x8;
typedef __attribute__((ext_vector_type(4))) short s16x4;
typedef __attribute__((ext_vector_type(4))) float f32x4;

#define MFMA16(a,b,c) __builtin_amdgcn_mfma_f32_16x16x32_bf16((a),(b),(c),0,0,0)

// soft barriers: raw s_barrier + counted waits
#define SOFT_BAR_LG() do{ asm volatile("s_waitcnt lgkmcnt(0)" ::: "memory"); \
  __builtin_amdgcn_s_barrier(); __builtin_amdgcn_sched_barrier(0); }while(0)
#define SOFT_BAR_VM(N) do{ asm volatile("s_waitcnt vmcnt(" #N ") lgkmcnt(0)" ::: "memory"); \
  __builtin_amdgcn_s_barrier(); __builtin_amdgcn_sched_barrier(0); }while(0)

__device__ __forceinline__ float bf2f(u16 u){ return __uint_as_float(((u32)u)<<16); }
__device__ __forceinline__ u16 f2bf(float f){
  u32 u = __float_as_uint(f);
  return (u16)((u + 0x7fffu + ((u>>16)&1u)) >> 16);
}
__device__ __forceinline__ u32 encf(float f){ u32 u=__float_as_uint(f); return (u&0x80000000u)? ~u : (u|0x80000000u); }
__device__ __forceinline__ float decf(u32 u){ return (u&0x80000000u)? __uint_as_float(u&0x7fffffffu) : __uint_as_float(~u); }

__device__ __forceinline__ void async_lds16(u16* lds, const u16* g){
  __builtin_amdgcn_global_load_lds((const __attribute__((address_space(1))) void*)g,
                                   (__attribute__((address_space(3))) void*)lds,
                                   16, 0, 0);
}

// stage ROWS x 64 bf16 from global into LDS padded to 72/row
template<int ROWS>
__device__ __forceinline__ void stage64(u16* dst, const u16* src, int srcStride, int tid){
  #pragma unroll
  for (int u=tid; u<ROWS*8; u+=256){
    int r=u>>3, c=(u&7)<<3;
    *(int4*)&dst[r*72+c] = *(const int4*)&src[(size_t)r*srcStride + c];
  }
}

// ---------------- init ----------------
__global__ void k_init(u32* kmaxEnc, u16* projS,
                       const float* __restrict__ proj, const float* __restrict__ x, u16* __restrict__ xb){
  int i = blockIdx.x*blockDim.x + threadIdx.x;
  int st = gridDim.x*blockDim.x;
  for (int j=i; j<32; j+=st) kmaxEnc[j]=0u;
  const float dn = 0.35355339059327373f; // 64^-0.25
  for (int j=i; j<512*64; j+=st) projS[j] = f2bf(dn*proj[j]);
  for (int j=i; j<524288; j+=st){
    float4 a = *(const float4*)&x[(size_t)j*8];
    float4 b = *(const float4*)&x[(size_t)j*8+4];
    u16 tmp[8] = {f2bf(a.x),f2bf(a.y),f2bf(a.z),f2bf(a.w),
                  f2bf(b.x),f2bf(b.y),f2bf(b.z),f2bf(b.w)};
    *(int4*)&xb[(size_t)j*8] = *(const int4*)tmp;
  }
}

// ---------------- fp32 512x512 -> bf16 transpose, batched over 4 weights ----------------
__global__ __launch_bounds__(256) void k_trw(const float* s0, const float* s1, const float* s2, const float* s3,
                                             u16* d0, u16* d1, u16* d2, u16* d3){
  int z = blockIdx.z;
  const float* src = z==0?s0:(z==1?s1:(z==2?s2:s3));
  u16* dst         = z==0?d0:(z==1?d1:(z==2?d2:d3));
  __shared__ u16 t[32][34];
  int c0=blockIdx.x*32, r0=blockIdx.y*32;
  int tid=threadIdx.x;
  for (int u=tid; u<1024; u+=256){ int r=u>>5, c=u&31; t[r][c]=f2bf(src[(size_t)(r0+r)*512 + c0+c]); }
  __syncthreads();
  for (int u=tid; u<1024; u+=256){ int c=u>>5, r=u&31; dst[(size_t)(c0+c)*512 + r0+r]=t[r][c]; }
}

// ---------------- v -> vT[bh][64][2048] ----------------
__global__ __launch_bounds__(256) void k_trv(const u16* __restrict__ v, u16* __restrict__ vT){
  int bh = blockIdx.z; int b=bh>>3, h=bh&7;
  int d0 = blockIdx.x*32, n0 = blockIdx.y*32;
  __shared__ u16 t[32][34];
  int tid=threadIdx.x;
  const u16* s = v + (size_t)(b*2048)*512 + h*64;
  for (int u=tid; u<1024; u+=256){ int r=u>>5, c=u&31; t[r][c]=s[(size_t)(n0+r)*512 + d0+c]; }
  __syncthreads();
  u16* d = vT + (size_t)bh*64*2048;
  for (int u=tid; u<1024; u+=256){ int c=u>>5, r=u&31; d[(size_t)(d0+c)*2048 + n0+r]=t[r][c]; }
}

// ---------------- vsum ----------------
__global__ __launch_bounds__(256) void k_vsum(const u16* __restrict__ vB, float* __restrict__ vsum){
  int bh=blockIdx.x; int b=bh>>3, h=bh&7;
  int tid=threadIdx.x; int d=tid&63, part=tid>>6;
  const u16* src = vB + (size_t)(b*2048 + part*512)*512 + h*64 + d;
  float s=0.f;
  for (int n=0;n<512;++n) s += bf2f(src[(size_t)n*512]);
  __shared__ float red[256];
  red[tid]=s; __syncthreads();
  if (part==0) vsum[bh*64+d]=red[d]+red[64+d]+red[128+d]+red[192+d];
}

// ---------------- diagK ----------------
__global__ __launch_bounds__(256) void k_kdiag(const u16* __restrict__ kB, float* __restrict__ diagK){
  int bh=blockIdx.x, seg=blockIdx.y;
  int b=bh>>3, h=bh&7;
  int tid=threadIdx.x;
  int part=tid&7;
  const u16* base = kB + (size_t)(b*2048 + seg*256)*512 + h*64 + part*8;
  for (int n0=0; n0<256; n0+=32){
    int n = n0 + (tid>>3);
    bf16x8 v = *(const bf16x8*)&base[(size_t)n*512];
    float sq=0.f;
    #pragma unroll
    for (int j=0;j<8;++j){ float f=bf2f((u16)v[j]); sq+=f*f; }
    sq += __shfl_xor(sq,1,64); sq += __shfl_xor(sq,2,64); sq += __shfl_xor(sq,4,64);
    if (part==0) diagK[(size_t)bh*2048 + seg*256 + n] = 0.0625f*sq;
  }
}

// ---------------- per-bh sums ----------------
__global__ __launch_bounds__(256) void k_sums(const u16* __restrict__ ctxT, const float* __restrict__ kcs,
                                              float* __restrict__ ctxsum, float* __restrict__ kcssum){
  int bh = blockIdx.x;
  int tid = threadIdx.x;
  int d = tid&63, part = tid>>6;
  const u16* src = ctxT + (size_t)bh*64*512 + (size_t)d*512 + part*128;
  float s=0.f;
  for (int m=0;m<128;m+=8){
    bf16x8 v = *(const bf16x8*)&src[m];
    #pragma unroll
    for (int j=0;j<8;++j) s += bf2f((u16)v[j]);
  }
  __shared__ float red[256];
  __shared__ float red2[256];
  red[tid]=s;
  float t=0.f;
  for (int u=tid;u<512;u+=256) t += kcs[(size_t)bh*512+u];
  red2[tid]=t;
  __syncthreads();
  if (part==0) ctxsum[bh*64+d] = red[d]+red[64+d]+red[128+d]+red[192+d];
  if (tid<64){
    float a=red2[tid]+red2[tid+64]+red2[tid+128]+red2[tid+192];
    #pragma unroll
    for (int m2=1;m2<64;m2<<=1) a += __shfl_xor(a,m2,64);
    if (tid==0) kcssum[bh]=a;
  }
}

// ---------------- GEMM, 2-deep async pipeline: O = A @ BT^T + bias ----------------
template<bool OF32>
__global__ __launch_bounds__(256) void k_gemm2(const u16* __restrict__ A,
    const u16* BT0, const u16* BT1, const u16* BT2,
    const float* b0, const float* b1, const float* b2,
    void* O0, void* O1, void* O2)
{
  int z = blockIdx.z;
  const u16* BT    = z==0?BT0:(z==1?BT1:BT2);
  const float* bias= z==0?b0 :(z==1?b1 :b2 );
  void* Ov         = z==0?O0 :(z==1?O1 :O2 );
  int bm = blockIdx.x*128, bn = blockIdx.y*64;
  __shared__ u16 sA[2][128*64];
  __shared__ u16 sB[2][64*64];
  int tid=threadIdx.x, w=tid>>6, lane=tid&63;
  int lr = lane>>3, lc = (lane&7)*8;
  f32x4 acc[8] = {};
  auto stage=[&](int bf, int koff){
    #pragma unroll
    for (int i=0;i<4;++i){
      int idx = w*4+i;
      async_lds16(&sA[bf][idx*512], A + (size_t)(bm + idx*8 + lr)*512 + koff + lc);
    }
    #pragma unroll
    for (int i=0;i<2;++i){
      int idx = w*2+i;
      async_lds16(&sB[bf][idx*512], BT + (size_t)(bn + idx*8 + lr)*512 + koff + lc);
    }
  };
  stage(0, 0);
  int fr = lane&15, kb=(lane>>4)*8;
  for (int kk=0; kk<8; ++kk){
    int cur = kk&1;
    if (kk<7) stage(cur^1, (kk+1)*64);
    if (kk<7) { SOFT_BAR_VM(6); } else { SOFT_BAR_VM(0); }
    #pragma unroll
    for (int rt=0; rt<2; ++rt){
      int ar = (w*2+rt)*16 + fr;
      #pragma unroll
      for (int ct=0; ct<4; ++ct){
        int br = ct*16 + fr;
        #pragma unroll
        for (int kc=0; kc<2; ++kc){
          bf16x8 av = *(const bf16x8*)&sA[cur][ar*64 + kc*32 + kb];
          bf16x8 bv = *(const bf16x8*)&sB[cur][br*64 + kc*32 + kb];
          acc[rt*4+ct] = MFMA16(av,bv,acc[rt*4+ct]);
        }
      }
    }
    SOFT_BAR_LG();
  }
  int colg = lane&15, rowg=(lane>>4)*4;
  #pragma unroll
  for (int rt=0; rt<2; ++rt){
    #pragma unroll
    for (int ct=0; ct<4; ++ct){
      int col = bn + ct*16 + colg;
      float bv = bias[col];
      #pragma unroll
      for (int j=0;j<4;++j){
        int row = bm + (w*2+rt)*16 + rowg + j;
        if constexpr (OF32) ((float*)Ov)[(size_t)row*512 + col] = acc[rt*4+ct][j] + bv;
        else                ((u16*) Ov)[(size_t)row*512 + col] = f2bf(acc[rt*4+ct][j] + bv);
      }
    }
  }
}

// ---------------- k features + ctx partial, quarter-n, 64-chunk, 4 blocks/CU ----------------
// grid (8 h, 32 = s*8+mblk, 4 b); s in 0..3 owns n-range [s*512, s*512+512).
__global__ __launch_bounds__(256) void k_kpctx4(const u16* __restrict__ kB, const u16* __restrict__ projS,
    const u16* __restrict__ vT, const float* __restrict__ diagK,
    float* __restrict__ ctxPT, float* __restrict__ kcsP, u32* __restrict__ kmaxEnc)
{
  int h=blockIdx.x, y=blockIdx.y, b=blockIdx.z;
  int mblk = y&7, s = y>>3;
  int bh=b*8+h;
  int m0 = mblk*64;
  __shared__ __align__(16) u16 pool[4*4608];   // sK | sV | sP | sT, each 64x72
  u16* sK=pool; u16* sV=pool+4608; u16* sP=pool+9216; u16* sT=pool+13824;
  __shared__ float sDg[64];
  __shared__ float red[4];
  int tid=threadIdx.x, w=tid>>6, lane=tid&63;
  int fr=lane&15, kb=(lane>>4)*8, rowg=(lane>>4)*4;
  stage64<64>(sP, projS + m0*64, 64, tid);
  f32x4 accc[4]={};
  float sS=0.f;
  float lm=-3.0e38f;
  const u16* gK = kB + (size_t)(b*2048 + s*512)*512 + h*64;
  const u16* gV = vT + (size_t)bh*64*2048 + s*512;
  const float* gD = diagK + (size_t)bh*2048 + s*512;
  int4 pK[2], pV[2]; float4 pD={0.f,0.f,0.f,0.f};
  #pragma unroll
  for (int i=0;i<2;++i){ int u=tid+i*256; int r=u>>3,c=(u&7)<<3; pK[i]=*(const int4*)&gK[(size_t)r*512 + c]; }
  #pragma unroll
  for (int i=0;i<2;++i){ int u=tid+i*256; int r=u>>3,c=(u&7)<<3; pV[i]=*(const int4*)&gV[(size_t)r*2048 + c]; }
  if (tid<16) pD = *(const float4*)&gD[tid*4];
  for (int nc=0; nc<8; ++nc){
    #pragma unroll
    for (int i=0;i<2;++i){ int u=tid+i*256; int r=u>>3,c=(u&7)<<3; *(int4*)&sK[r*72+c]=pK[i]; }
    #pragma unroll
    for (int i=0;i<2;++i){ int u=tid+i*256; int r=u>>3,c=(u&7)<<3; *(int4*)&sV[r*72+c]=pV[i]; }
    if (tid<16) *(float4*)&sDg[tid*4] = pD;
    SOFT_BAR_LG();
    if (nc<7){
      #pragma unroll
      for (int i=0;i<2;++i){ int u=tid+i*256; int r=u>>3,c=(u&7)<<3; pK[i]=*(const int4*)&gK[(size_t)((nc+1)*64+r)*512 + c]; }
      #pragma unroll
      for (int i=0;i<2;++i){ int u=tid+i*256; int r=u>>3,c=(u&7)<<3; pV[i]=*(const int4*)&gV[(size_t)r*2048 + (nc+1)*64 + c]; }
      if (tid<16) pD = *(const float4*)&gD[(nc+1)*64 + tid*4];
    }
    // feature MFMA: dd[64 n][64 m], wave w owns n rows w*16..+15
    int ar = w*16 + fr;
    f32x4 facc[4];
    #pragma unroll
    for (int mt=0;mt<4;++mt){
      f32x4 a={0.f,0.f,0.f,0.f};
      a=MFMA16(*(const bf16x8*)&sK[ar*72+kb],    *(const bf16x8*)&sP[(mt*16+fr)*72+kb],    a);
      a=MFMA16(*(const bf16x8*)&sK[ar*72+32+kb], *(const bf16x8*)&sP[(mt*16+fr)*72+32+kb], a);
      facc[mt]=a;
      lm=fmaxf(lm, fmaxf(fmaxf(a[0],a[1]),fmaxf(a[2],a[3])));
    }
    // exp -> sT[m][n]
    {
      int nl = w*16 + rowg;
      #pragma unroll
      for (int mt=0;mt<4;++mt){
        int ml=mt*16+fr;
        s16x4 pk;
        #pragma unroll
        for (int j=0;j<4;++j) pk[j]=(short)f2bf(__expf(facc[mt][j]-sDg[nl+j]));
        *(s16x4*)&sT[ml*72+nl]=pk;
      }
    }
    SOFT_BAR_LG();
    // PV: ctx[m][d] += sT[64m][64n] @ sV[64d][64n]^T ; wave w owns m rows w*16..+15
    int am=w*16+fr;
    #pragma unroll
    for (int ct=0;ct<4;++ct){
      #pragma unroll
      for (int ks=0;ks<2;++ks){
        accc[ct]=MFMA16(*(const bf16x8*)&sT[am*72+ks*32+kb],
                        *(const bf16x8*)&sV[(ct*16+fr)*72+ks*32+kb], accc[ct]);
      }
    }
    {
      int m=tid>>2, q=tid&3;
      #pragma unroll
      for (int n8=0;n8<2;++n8){
        bf16x8 v=*(const bf16x8*)&sT[m*72+q*16+n8*8];
        #pragma unroll
        for (int j=0;j<8;++j) sS += bf2f((u16)v[j]);
      }
    }
    SOFT_BAR_LG();
  }
  // S partial store
  {
    int m=tid>>2, q=tid&3;
    float t=sS;
    t += __shfl_xor(t,1,64); t += __shfl_xor(t,2,64);
    if (q==0) kcsP[(size_t)(s*32+bh)*512 + m0 + m] = t;
  }
  // mk
  #pragma unroll
  for (int m2=1;m2<64;m2<<=1) lm=fmaxf(lm,__shfl_xor(lm,m2,64));
  if (lane==0) red[w]=lm;
  __syncthreads();
  if (tid==0) atomicMax(&kmaxEnc[bh], encf(fmaxf(fmaxf(red[0],red[1]),fmaxf(red[2],red[3]))));
  // ctx partial f32 transposed bounce: float[64 d][68] reuses pool start (sK/sV/sP region, dead now)
  float* sTf = (float*)pool;
  int mloc = w*16+rowg;
  #pragma unroll
  for (int ct=0;ct<4;++ct){
    #pragma unroll
    for (int j=0;j<4;++j) sTf[(ct*16+fr)*68 + mloc + j] = accc[ct][j];
  }
  __syncthreads();
  for (int u=tid; u<1024; u+=256){
    int r=u>>4, c=(u&15)*4;
    *(float4*)&ctxPT[((size_t)(s*32+bh)*64 + r)*512 + m0 + c] = *(const float4*)&sTf[r*68+c];
  }
}

// ---------------- combine 4 split-n partials -> ctxT bf16 + kcs ----------------
__global__ __launch_bounds__(256) void k_comb(const float* __restrict__ ctxPT, u16* __restrict__ ctxT,
                                              const float* __restrict__ kcsP, float* __restrict__ kcs){
  int bh=blockIdx.x, dblk=blockIdx.y;
  int tid=threadIdx.x;
  int d0=dblk*8;
  u16* o = ctxT + ((size_t)bh*64 + d0)*512;
  for (int u=tid; u<1024; u+=256){
    int r=u>>7, c=(u&127)*4;
    float4 a={0.f,0.f,0.f,0.f};
    #pragma unroll
    for (int s=0;s<4;++s){
      float4 p=*(const float4*)&ctxPT[((size_t)(s*32+bh)*64 + d0+r)*512 + c];
      a.x+=p.x; a.y+=p.y; a.z+=p.z; a.w+=p.w;
    }
    u16 t[4]={f2bf(a.x),f2bf(a.y),f2bf(a.z),f2bf(a.w)};
    *(int2*)&o[(size_t)r*512+c] = *(const int2*)t;
  }
  if (dblk==0){
    for (int u=tid; u<512; u+=256){
      float t=0.f;
      #pragma unroll
      for (int s=0;s<4;++s) t += kcsP[(size_t)(s*32+bh)*512+u];
      kcs[(size_t)bh*512+u]=t;
    }
  }
}

// ---------------- q features + PV + eps epilogue: 64 rows/block, swizzled LDS, 4 blocks/CU ----------------
// grid (8 h, 32 chunk, 4 b). T2 swizzle: linear LDS dest, source granule gl = gp ^ (row&7),
// reads XOR the same involution -> 16-way bank conflict becomes 2-way (free).
__global__ __launch_bounds__(256) void k_qpout3(const u16* __restrict__ qB, const u16* __restrict__ projS,
    const float* __restrict__ kcs, const u16* __restrict__ ctxT,
    const float* __restrict__ ctxsum, const float* __restrict__ kcssum,
    const float* __restrict__ vsum, const u32* __restrict__ kmaxEnc,
    u16* __restrict__ outc)
{
  int h=blockIdx.x, chunk=blockIdx.y, b=blockIdx.z;
  int bh=b*8+h;
  int t0 = b*2048 + chunk*64;
  __shared__ u16 sP[2][64*64];
  __shared__ u16 sCt[64*64];
  __shared__ u16 qpL[64*72];
  __shared__ float sK[512];
  __shared__ float diag[64];
  int tid=threadIdx.x, w=tid>>6, lane=tid&63;
  int fr=lane&15, kbg=lane>>4, kb=kbg*8, rowg=kbg*4;
  int lr=lane>>3, lgl=((lane&7)^lr)*8;   // swizzled source granule offset (elems)
  int sw=fr&7;                            // read-side XOR key (row&7)
  bf16x8 qf[2];
  #pragma unroll
  for (int kc=0;kc<2;++kc)
    qf[kc] = *(const bf16x8*)&qB[(size_t)(t0 + w*16 + fr)*512 + h*64 + kc*32 + kb];
  {
    float ssum=0.f;
    #pragma unroll
    for (int kc=0;kc<2;++kc)
      #pragma unroll
      for (int j=0;j<8;++j){ float f=bf2f((u16)qf[kc][j]); ssum+=f*f; }
    ssum += __shfl_xor(ssum,16,64); ssum += __shfl_xor(ssum,32,64);
    if (lane<16) diag[w*16 + fr] = 0.0625f*ssum;
  }
  for (int u=tid; u<512; u+=256) sK[u] = kcs[(size_t)bh*512 + u];
  const u16* gcB = ctxT + (size_t)bh*64*512;
  // prologue: stage sP(0), swizzled source
  #pragma unroll
  for (int i=0;i<2;++i){
    int idx = w*2+i;
    async_lds16(&sP[0][idx*512], projS + (size_t)(idx*8+lr)*64 + lgl);
  }
  f32x4 acc2[4]={};
  float mx[4], dp[4], rs[4];
  #pragma unroll
  for (int j=0;j<4;++j){ mx[j]=-3.0e38f; dp[j]=0.f; rs[j]=0.f; }
  SOFT_BAR_VM(0);
  for (int mc=0; mc<8; ++mc){
    int cur = mc&1;
    // A: issue sCt(mc), then sP(mc+1) — both swizzled-source
    #pragma unroll
    for (int i=0;i<2;++i){
      int idx = w*2+i;
      async_lds16(&sCt[idx*512], gcB + (size_t)(idx*8+lr)*512 + mc*64 + lgl);
    }
    if (mc<7){
      const u16* gp = projS + (mc+1)*64*64;
      #pragma unroll
      for (int i=0;i<2;++i){
        int idx = w*2+i;
        async_lds16(&sP[cur^1][idx*512], gp + (size_t)(idx*8+lr)*64 + lgl);
      }
    }
    // B: feature MFMA on sP[cur] (swizzled read)
    f32x4 facc[4];
    #pragma unroll
    for (int mt=0;mt<4;++mt){
      f32x4 a={0.f,0.f,0.f,0.f};
      #pragma unroll
      for (int kc=0;kc<2;++kc){
        bf16x8 bv = *(const bf16x8*)&sP[cur][(mt*16+fr)*64 + (((kc*4+kbg)^sw)<<3)];
        a = MFMA16(qf[kc], bv, a);
      }
      facc[mt]=a;
    }
    // exp -> qpL (wave-private rows w*16..w*16+15)
    #pragma unroll
    for (int mt=0;mt<4;++mt){
      #pragma unroll
      for (int j=0;j<4;++j){
        int rl = w*16 + rowg + j;
        mx[j] = fmaxf(mx[j], facc[mt][j]);
        float vq = __expf(facc[mt][j] - diag[rl]);
        u16 us = f2bf(vq);
        qpL[rl*72 + mt*16 + fr] = us;
        float uf = bf2f(us);
        dp[j] += uf*sK[mc*64 + mt*16 + fr];
        rs[j] += uf;
      }
    }
    // C: retire sCt (keep sP(mc+1) in flight), publish
    if (mc<7) { SOFT_BAR_VM(2); } else { SOFT_BAR_VM(0); }
    // D: PV on qpL (same wave) + sCt (swizzled read)
    #pragma unroll
    for (int ct=0;ct<4;++ct){
      #pragma unroll
      for (int kc=0;kc<2;++kc){
        bf16x8 av = *(const bf16x8*)&qpL[(w*16+fr)*72 + kc*32 + kb];
        bf16x8 bv = *(const bf16x8*)&sCt[(ct*16+fr)*64 + (((kc*4+kbg)^sw)<<3)];
        acc2[ct] = MFMA16(av,bv,acc2[ct]);
      }
    }
    // E: retire sP(mc+1) + publish; protects sCt overwrite next chunk
    if (mc<7) { SOFT_BAR_VM(0); }
  }
  #pragma unroll
  for (int j=0;j<4;++j){
    #pragma unroll
    for (int s=1;s<16;s<<=1){
      dp[j] += __shfl_xor(dp[j],s,64);
      rs[j] += __shfl_xor(rs[j],s,64);
      mx[j]  = fmaxf(mx[j], __shfl_xor(mx[j],s,64));
    }
  }
  float mk  = decf(kmaxEnc[bh]);
  float emk = __expf(mk);
  float Ssum = kcssum[bh];
  const float eps=1e-4f;
  float emq[4];
  #pragma unroll
  for (int j=0;j<4;++j) emq[j]=__expf(mx[j]);
  #pragma unroll
  for (int ct=0;ct<4;++ct){
    int d = ct*16 + fr;
    float cs = ctxsum[bh*64 + d];
    float vs = vsum[bh*64 + d];
    #pragma unroll
    for (int j=0;j<4;++j){
      float eq = emq[j];
      float numer = acc2[ct][j] + eps*(emk*vs*rs[j] + eq*cs + eps*eq*emk*512.0f*vs);
      float den   = dp[j]       + eps*(emk*2048.0f*rs[j] + eq*Ssum + eps*eq*emk*512.0f*2048.0f);
      int row = t0 + w*16 + rowg + j;
      outc[(size_t)row*512 + h*64 + d] = f2bf(numer/den);
    }
  }
}

extern "C" void kernel_launch(void* const* d_in, const int* in_sizes, int n_in,
                              void* d_out, int out_size, void* d_ws, size_t ws_size,
                              hipStream_t stream)
{
  (void)in_sizes; (void)n_in; (void)out_size; (void)ws_size;
  const float* x    = (const float*)d_in[0];
  const float* Wq   = (const float*)d_in[1];
  const float* bq   = (const float*)d_in[2];
  const float* Wk   = (const float*)d_in[3];
  const float* bk   = (const float*)d_in[4];
  const float* Wv   = (const float*)d_in[5];
  const float* bv   = (const float*)d_in[6];
  const float* Wo   = (const float*)d_in[7];
  const float* bo   = (const float*)d_in[8];
  const float* proj = (const float*)d_in[9];

  char* w = (char*)d_ws;
  size_t off=0;
  auto alloc=[&](size_t bytes)->char*{ char* p=w+off; off=(off+bytes+255)&~(size_t)255; return p; };
  u16*  xb   = (u16*)alloc(8192ull*512*2);
  u16*  qB   = (u16*)alloc(8192ull*512*2);
  u16*  kBf  = (u16*)alloc(8192ull*512*2);
  u16*  vB   = (u16*)alloc(8192ull*512*2);
  u16*  vT   = (u16*)alloc(32ull*64*2048*2);
  u16*  WqT  = (u16*)alloc(512ull*512*2);
  u16*  WkT  = (u16*)alloc(512ull*512*2);
  u16*  WvT  = (u16*)alloc(512ull*512*2);
  u16*  WoT  = (u16*)alloc(512ull*512*2);
  u16*  projS= (u16*)alloc(512ull*64*2);
  u16*  ctxT = (u16*)alloc(32ull*64*512*2);
  float* ctxPT=(float*)alloc(4ull*32*64*512*4);
  float* kcs = (float*)alloc(32ull*512*4);
  float* kcsP= (float*)alloc(4ull*32*512*4);
  float* diagK=(float*)alloc(32ull*2048*4);
  u32*  kmx  = (u32*)alloc(256);
  float* ctxs= (float*)alloc(32ull*64*4);
  float* kcss= (float*)alloc(32ull*4);
  float* vsm = (float*)alloc(32ull*64*4);
  u16*  outc = kBf;  // kBf dead after k_kpctx4; reuse

  dim3 TB(256);
  k_init<<<dim3(256),TB,0,stream>>>(kmx,projS,proj,x,xb);
  k_trw<<<dim3(16,16,4),TB,0,stream>>>(Wq,Wk,Wv,Wo, WqT,WkT,WvT,WoT);
  k_gemm2<false><<<dim3(64,8,3),TB,0,stream>>>(xb, WqT,WkT,WvT, bq,bk,bv, qB,kBf,vB);
  k_trv<<<dim3(2,64,32),TB,0,stream>>>(vB, vT);
  k_vsum<<<dim3(32),TB,0,stream>>>(vB, vsm);
  k_kdiag<<<dim3(32,8),TB,0,stream>>>(kBf, diagK);
  k_kpctx4<<<dim3(8,32,4),TB,0,stream>>>(kBf, projS, vT, diagK, ctxPT, kcsP, kmx);
  k_comb<<<dim3(32,8),TB,0,stream>>>(ctxPT, ctxT, kcsP, kcs);
  k_sums<<<dim3(32),TB,0,stream>>>(ctxT, kcs, ctxs, kcss);
  k_qpout3<<<dim3(8,32,4),TB,0,stream>>>(qB, projS, kcs, ctxT, ctxs, kcss, vsm, kmx, outc);
  k_gemm2<true><<<dim3(64,8,1),TB,0,stream>>>(outc, WoT,WoT,WoT, bo,bo,bo,
                                              d_out,d_out,d_out);
}